// Round 11
// baseline (2024.628 us; speedup 1.0000x reference)
//
#include <hip/hip_runtime.h>
#include <math.h>

#define Bn 128
#define Tn 512
#define Dn 32
#define Hn 128
#define Gn 512   // 4*H
#define Ln 3

// LDS-only barrier: does NOT drain vmcnt.
#define BAR_LDS() asm volatile("s_waitcnt lgkmcnt(0)\n\ts_barrier" ::: "memory")

typedef _Float16 h2 __attribute__((ext_vector_type(2)));

__device__ __forceinline__ float dot2(h2 a, h2 b, float c) {
    return __builtin_amdgcn_fdot2(a, b, c, false);
}
__device__ __forceinline__ h2 pkh(float a, float b) {
    h2 r; r.x = (_Float16)a; r.y = (_Float16)b; return r;
}
__device__ __forceinline__ h2 bcast2(h2 v, int l) {
    int i = __builtin_amdgcn_readlane(__builtin_bit_cast(int, v), l);
    return __builtin_bit_cast(h2, i);
}
__device__ __forceinline__ float sigm(float x) {
    return __builtin_amdgcn_rcpf(1.f + __expf(-x));
}
__device__ __forceinline__ float tanh_fast(float x) {
    return 1.f - 2.f * __builtin_amdgcn_rcpf(1.f + __expf(2.f * x));
}

#define KEEPH(x) asm volatile("" : "+v"(x))
// 16 packed half2 from 32 floats at R, RE-PAIRED: pair j = (R[j], R[16+j]).
// This makes update lane p own units (32kq+p, 32kq+16+p): 16B-stride psum
// reads (conflict-free) and a local 3-inst h-pack (no cross-lane pack).
#define DECL16P(P, R) \
  h2 P##0 =pkh(R[0], R[16]), P##1 =pkh(R[1], R[17]), P##2 =pkh(R[2], R[18]),  \
     P##3 =pkh(R[3], R[19]), P##4 =pkh(R[4], R[20]), P##5 =pkh(R[5], R[21]),  \
     P##6 =pkh(R[6], R[22]), P##7 =pkh(R[7], R[23]), P##8 =pkh(R[8], R[24]),  \
     P##9 =pkh(R[9], R[25]), P##10=pkh(R[10],R[26]), P##11=pkh(R[11],R[27]),  \
     P##12=pkh(R[12],R[28]), P##13=pkh(R[13],R[29]), P##14=pkh(R[14],R[30]),  \
     P##15=pkh(R[15],R[31]);
#define KEEP16(P) \
  KEEPH(P##0); KEEPH(P##1); KEEPH(P##2); KEEPH(P##3); KEEPH(P##4); KEEPH(P##5); \
  KEEPH(P##6); KEEPH(P##7); KEEPH(P##8); KEEPH(P##9); KEEPH(P##10); KEEPH(P##11); \
  KEEPH(P##12); KEEPH(P##13); KEEPH(P##14); KEEPH(P##15);

// One broadcast pair feeds 4 dot2 (i,f,g,o of this thread's unit).
#define DOT4(j) { h2 s = bcast2(hp, j);      \
    aI = dot2(s, wi##j, aI);                 \
    aF = dot2(s, wf##j, aF);                 \
    aG = dot2(s, wg##j, aG);                 \
    aO = dot2(s, wo##j, aO); }

// ---------------------------------------------------------------------------
// GEMM: pre[M, 512] = A_chunk[M, K] * W[512, K]^T + (b_ih + b_hh)
// ---------------------------------------------------------------------------
__global__ __launch_bounds__(256) void gemm_pre(
    const float* __restrict__ A, int K, int rowStrideB, int t0, int tlog,
    const float* __restrict__ W,
    const float* __restrict__ bi, const float* __restrict__ bh,
    float* __restrict__ C)
{
    __shared__ __align__(16) float As[8][128];
    __shared__ __align__(16) float Bs[8][128];
    const int tid  = threadIdx.x;
    const int row0 = blockIdx.x * 128;
    const int col0 = blockIdx.y * 128;
    const int ty = tid >> 4, tx = tid & 15;
    const int lr = tid >> 1, lk = (tid & 1) * 4;
    const int tmask = (1 << tlog) - 1;

    float acc[8][8];
    #pragma unroll
    for (int i = 0; i < 8; i++)
        #pragma unroll
        for (int j = 0; j < 8; j++) acc[i][j] = 0.f;

    for (int k0 = 0; k0 < K; k0 += 8) {
        {
            int rg = row0 + lr;
            int b_idx = rg >> tlog;
            int tt = rg & tmask;
            const float* ap = A + (size_t)b_idx * rowStrideB +
                              (size_t)(t0 + tt) * K + (k0 + lk);
            float4 av = *(const float4*)ap;
            As[lk + 0][lr] = av.x; As[lk + 1][lr] = av.y;
            As[lk + 2][lr] = av.z; As[lk + 3][lr] = av.w;
            const float* wp = W + (size_t)(col0 + lr) * K + (k0 + lk);
            float4 wv = *(const float4*)wp;
            Bs[lk + 0][lr] = wv.x; Bs[lk + 1][lr] = wv.y;
            Bs[lk + 2][lr] = wv.z; Bs[lk + 3][lr] = wv.w;
        }
        __syncthreads();
        #pragma unroll
        for (int kk = 0; kk < 8; kk++) {
            float4 a0 = *(const float4*)&As[kk][ty * 8];
            float4 a1 = *(const float4*)&As[kk][ty * 8 + 4];
            float4 b0 = *(const float4*)&Bs[kk][tx * 8];
            float4 b1v = *(const float4*)&Bs[kk][tx * 8 + 4];
            float av[8] = {a0.x, a0.y, a0.z, a0.w, a1.x, a1.y, a1.z, a1.w};
            float bv[8] = {b0.x, b0.y, b0.z, b0.w, b1v.x, b1v.y, b1v.z, b1v.w};
            #pragma unroll
            for (int i = 0; i < 8; i++)
                #pragma unroll
                for (int j = 0; j < 8; j++) acc[i][j] += av[i] * bv[j];
        }
        __syncthreads();
    }
    #pragma unroll
    for (int i = 0; i < 8; i++) {
        int r = row0 + ty * 8 + i;
        #pragma unroll
        for (int j = 0; j < 8; j += 4) {
            int g = col0 + tx * 8 + j;
            float4 o;
            o.x = acc[i][j + 0] + bi[g + 0] + bh[g + 0];
            o.y = acc[i][j + 1] + bi[g + 1] + bh[g + 1];
            o.z = acc[i][j + 2] + bi[g + 2] + bh[g + 2];
            o.w = acc[i][j + 3] + bi[g + 3] + bh[g + 3];
            *(float4*)&C[(size_t)r * Gn + g] = o;
        }
    }
}

// ---------------------------------------------------------------------------
// LSTM scan v7. 512 threads (8 waves), one block per batch item.
// v5 mapping: thread (u = tid&127, kq = tid>>7) computes gates i,f,g,o of
// unit u over k in [32kq,32kq+32) with 64 pinned half2 weights + fdot2.
// ONE barrier/step: psum[2][4][128] double-buffered. Each group kq's update
// lanes (lane<16, both waves, replicated) reduce psum for the 32 units of
// their OWN k-window and carry h,c in registers -- the recurrent state
// never touches LDS, and next step's broadcasts are intra-wave readlanes.
// ---------------------------------------------------------------------------
__global__ __launch_bounds__(512)
__attribute__((amdgpu_waves_per_eu(2, 2)))
void lstm_scan(
    const float* __restrict__ pre,     // [B*TCH, 512]
    const float* __restrict__ w_hh,    // [512, 128] (this layer)
    float* __restrict__ hs,            // [B, T, H] layer output (fp32)
    float* __restrict__ h_state, float* __restrict__ c_state,
    int t0, int TCH, int first)
{
    const int b    = blockIdx.x;
    const int tid  = threadIdx.x;
    const int lane = tid & 63;
    const int u    = tid & 127;        // this thread's dot unit
    const int kq   = tid >> 7;         // k-quarter / group id
    const bool upd = (lane < 16);
    const bool st  = upd && ((tid & 64) == 0);   // store-gating (1 wave/group)
    const int m0 = 32 * kq + lane;          // update unit A (lane<16)
    const int m1 = m0 + 16;                 // update unit B

    __shared__ __align__(16) float4 psum[2][4][Hn];   // 16 KB

    // --- weights: 4 gates x 32 k = 16 half2 per gate, re-paired ---
    const float* rI = w_hh + (size_t)(0 * Hn + u) * Hn + kq * 32;
    const float* rF = w_hh + (size_t)(1 * Hn + u) * Hn + kq * 32;
    const float* rG = w_hh + (size_t)(2 * Hn + u) * Hn + kq * 32;
    const float* rO = w_hh + (size_t)(3 * Hn + u) * Hn + kq * 32;
    DECL16P(wi, rI) DECL16P(wf, rF) DECL16P(wg, rG) DECL16P(wo, rO)
    KEEP16(wi) KEEP16(wf) KEEP16(wg) KEEP16(wo)

    // --- recurrent state (registers of update lanes) ---
    float c0 = 0.f, c1 = 0.f;
    h2 hp = pkh(0.f, 0.f);
    if (upd && !first) {
        float ha = h_state[b * Hn + m0];
        float hb_ = h_state[b * Hn + m1];
        c0 = c_state[b * Hn + m0];
        c1 = c_state[b * Hn + m1];
        hp = pkh(ha, hb_);
    }

    const float* pb = pre + (size_t)b * TCH * Gn;
    float* hsb = hs + ((size_t)b * Tn + t0) * Hn;

    // pre prefetch (update lanes): 8 gates = {I,F,G,O} x {m0,m1}, depth 2
    float pI0a=0.f,pF0a=0.f,pG0a=0.f,pO0a=0.f, pI0b=0.f,pF0b=0.f,pG0b=0.f,pO0b=0.f;
    float pI1a=0.f,pF1a=0.f,pG1a=0.f,pO1a=0.f, pI1b=0.f,pF1b=0.f,pG1b=0.f,pO1b=0.f;
    if (upd) {
        pI0a = pb[0*Hn+m0]; pF0a = pb[1*Hn+m0]; pG0a = pb[2*Hn+m0]; pO0a = pb[3*Hn+m0];
        pI0b = pb[0*Hn+m1]; pF0b = pb[1*Hn+m1]; pG0b = pb[2*Hn+m1]; pO0b = pb[3*Hn+m1];
        const float* p1 = pb + ((TCH > 1) ? Gn : 0);
        pI1a = p1[0*Hn+m0]; pF1a = p1[1*Hn+m0]; pG1a = p1[2*Hn+m0]; pO1a = p1[3*Hn+m0];
        pI1b = p1[0*Hn+m1]; pF1b = p1[1*Hn+m1]; pG1b = p1[2*Hn+m1]; pO1b = p1[3*Hn+m1];
    }

    for (int t = 0; t < TCH; t++) {
        const int buf = t & 1;

        // dot phase (all lanes): broadcasts from this wave's update lanes
        float aI = 0.f, aF = 0.f, aG = 0.f, aO = 0.f;
        DOT4(0)  DOT4(1)  DOT4(2)  DOT4(3)
        DOT4(4)  DOT4(5)  DOT4(6)  DOT4(7)
        DOT4(8)  DOT4(9)  DOT4(10) DOT4(11)
        DOT4(12) DOT4(13) DOT4(14) DOT4(15)
        psum[buf][kq][u] = make_float4(aI, aF, aG, aO);
        BAR_LDS();

        if (upd) {
            // prefetch pre[t+2] (stays in flight)
            int tn = (t + 2 < TCH) ? (t + 2) : (TCH - 1);
            const float* p = pb + (size_t)tn * Gn;
            float nIa = p[0*Hn+m0], nFa = p[1*Hn+m0], nGa = p[2*Hn+m0], nOa = p[3*Hn+m0];
            float nIb = p[0*Hn+m1], nFb = p[1*Hn+m1], nGb = p[2*Hn+m1], nOb = p[3*Hn+m1];

            // reduce 4 k-windows for units m0, m1 (16B-stride: conflict-free)
            float4 s0 = psum[buf][0][m0], s1 = psum[buf][1][m0];
            float4 s2 = psum[buf][2][m0], s3 = psum[buf][3][m0];
            float4 r0 = psum[buf][0][m1], r1 = psum[buf][1][m1];
            float4 r2 = psum[buf][2][m1], r3 = psum[buf][3][m1];
            float giA = ((s0.x + s1.x) + (s2.x + s3.x)) + pI0a;
            float gfA = ((s0.y + s1.y) + (s2.y + s3.y)) + pF0a;
            float ggA = ((s0.z + s1.z) + (s2.z + s3.z)) + pG0a;
            float goA = ((s0.w + s1.w) + (s2.w + s3.w)) + pO0a;
            float giB = ((r0.x + r1.x) + (r2.x + r3.x)) + pI0b;
            float gfB = ((r0.y + r1.y) + (r2.y + r3.y)) + pF0b;
            float ggB = ((r0.z + r1.z) + (r2.z + r3.z)) + pG0b;
            float goB = ((r0.w + r1.w) + (r2.w + r3.w)) + pO0b;

            float ivA = sigm(giA), fvA = sigm(gfA);
            float gvA = tanh_fast(ggA), ovA = sigm(goA);
            c0 = fvA * c0 + ivA * gvA;
            float hA = ovA * tanh_fast(c0);
            float ivB = sigm(giB), fvB = sigm(gfB);
            float gvB = tanh_fast(ggB), ovB = sigm(goB);
            c1 = fvB * c1 + ivB * gvB;
            float hB = ovB * tanh_fast(c1);
            hp = pkh(hA, hB);

            if (st) {                            // one wave per group stores
                hsb[(size_t)t * Hn + m0] = hA;
                hsb[(size_t)t * Hn + m1] = hB;
            }

            pI0a = pI1a; pF0a = pF1a; pG0a = pG1a; pO0a = pO1a;
            pI0b = pI1b; pF0b = pF1b; pG0b = pG1b; pO0b = pO1b;
            pI1a = nIa;  pF1a = nFa;  pG1a = nGa;  pO1a = nOa;
            pI1b = nIb;  pF1b = nFb;  pG1b = nGb;  pO1b = nOb;
        }
    }

    if (st) {
        h2 hv = hp;
        h_state[b * Hn + m0] = (float)hv.x;
        h_state[b * Hn + m1] = (float)hv.y;
        c_state[b * Hn + m0] = c0;
        c_state[b * Hn + m1] = c1;
    }
}

// ---------------------------------------------------------------------------
// Attention pooling + MLP head. One block per batch item, 256 threads.
// ---------------------------------------------------------------------------
__global__ __launch_bounds__(256) void head_kernel(
    const float* __restrict__ hs,
    const float* __restrict__ w_attn, const float* __restrict__ b_attn,
    const float* __restrict__ w1, const float* __restrict__ b1,
    const float* __restrict__ w2, const float* __restrict__ b2,
    float* __restrict__ out)
{
    const int b = blockIdx.x;
    const int tid = threadIdx.x;
    __shared__ __align__(16) float wa_sh[Hn];
    __shared__ __align__(16) float sc[Tn];
    __shared__ __align__(16) float red[256];
    __shared__ __align__(16) float ctx_sh[Hn];
    __shared__ __align__(16) float h1_sh[64];

    if (tid < Hn) wa_sh[tid] = w_attn[tid];
    __syncthreads();

    const float* hb = hs + (size_t)b * Tn * Hn;

    for (int t = tid; t < Tn; t += 256) {
        const float4* hv = (const float4*)(hb + (size_t)t * Hn);
        const float4* wvv = (const float4*)wa_sh;
        float s = 0.f;
        #pragma unroll
        for (int k = 0; k < 32; k++) {
            float4 h4 = hv[k], w4 = wvv[k];
            s += h4.x * w4.x + h4.y * w4.y + h4.z * w4.z + h4.w * w4.w;
        }
        sc[t] = s + b_attn[0];
    }
    __syncthreads();

    float m = fmaxf(sc[tid], sc[tid + 256]);
    red[tid] = m; __syncthreads();
    for (int s_ = 128; s_ > 0; s_ >>= 1) {
        if (tid < s_) red[tid] = fmaxf(red[tid], red[tid + s_]);
        __syncthreads();
    }
    float mx = red[0];
    __syncthreads();
    float e0 = __expf(sc[tid] - mx), e1 = __expf(sc[tid + 256] - mx);
    sc[tid] = e0; sc[tid + 256] = e1;
    red[tid] = e0 + e1; __syncthreads();
    for (int s_ = 128; s_ > 0; s_ >>= 1) {
        if (tid < s_) red[tid] += red[tid + s_];
        __syncthreads();
    }
    float inv = 1.f / red[0];
    __syncthreads();

    {
        int jj = tid & 127, half = tid >> 7;
        float a = 0.f;
        for (int t = half * 256; t < half * 256 + 256; t++)
            a += sc[t] * hb[(size_t)t * Hn + jj];
        red[tid] = a;
        __syncthreads();
        if (tid < Hn) ctx_sh[tid] = (red[tid] + red[tid + Hn]) * inv;
        __syncthreads();
    }

    if (tid < 64) {
        const float4* wvv = (const float4*)(w1 + (size_t)tid * Hn);
        const float4* cv = (const float4*)ctx_sh;
        float s = 0.f;
        #pragma unroll
        for (int k = 0; k < 32; k++) {
            float4 a = wvv[k], c = cv[k];
            s += a.x * c.x + a.y * c.y + a.z * c.z + a.w * c.w;
        }
        h1_sh[tid] = fmaxf(s + b1[tid], 0.f);
    }
    __syncthreads();

    if (tid < 4) {
        float s = 0.f;
        const float* wvv = w2 + tid * 64;
        #pragma unroll
        for (int k = 0; k < 64; k++) s += wvv[k] * h1_sh[k];
        out[b * 4 + tid] = s + b2[tid];
    }
}

// ---------------------------------------------------------------------------
extern "C" void kernel_launch(void* const* d_in, const int* in_sizes, int n_in,
                              void* d_out, int out_size, void* d_ws, size_t ws_size,
                              hipStream_t stream)
{
    const float* x        = (const float*)d_in[0];
    const float* w_ih0    = (const float*)d_in[1];
    const float* w_ih_rest= (const float*)d_in[2];
    const float* w_hh     = (const float*)d_in[3];
    const float* b_ih     = (const float*)d_in[4];
    const float* b_hh     = (const float*)d_in[5];
    const float* w_attn   = (const float*)d_in[6];
    const float* b_attn   = (const float*)d_in[7];
    const float* w1       = (const float*)d_in[8];
    const float* b1       = (const float*)d_in[9];
    const float* w2       = (const float*)d_in[10];
    const float* b2       = (const float*)d_in[11];
    float* out = (float*)d_out;

    float* ws   = (float*)d_ws;
    float* hs   = ws;
    float* h_st = hs + (size_t)Bn * Tn * Hn;
    float* c_st = h_st + (size_t)Bn * Hn;
    float* pre  = c_st + (size_t)Bn * Hn;

    int tch = 512;
    while (tch > 16) {
        size_t need = ((size_t)Bn * Tn * Hn + 2 * (size_t)Bn * Hn +
                       (size_t)Bn * tch * Gn) * sizeof(float);
        if (need <= ws_size) break;
        tch >>= 1;
    }
    int tlog = 31 - __builtin_clz((unsigned)tch);

    for (int l = 0; l < Ln; l++) {
        const float* A = (l == 0) ? x : hs;
        int K = (l == 0) ? Dn : Hn;
        const float* W = (l == 0) ? w_ih0 : (w_ih_rest + (size_t)(l - 1) * Gn * Hn);
        const float* whl = w_hh + (size_t)l * Gn * Hn;
        for (int c = 0; c < Tn / tch; c++) {
            dim3 gg(tch, 4);
            gemm_pre<<<gg, 256, 0, stream>>>(A, K, Tn * K, c * tch, tlog,
                                             W, b_ih + l * Gn, b_hh + l * Gn, pre);
            lstm_scan<<<Bn, 512, 0, stream>>>(pre, whl, hs, h_st, c_st,
                                              c * tch, tch, c == 0 ? 1 : 0);
        }
    }
    head_kernel<<<Bn, 256, 0, stream>>>(hs, w_attn, b_attn, w1, b1, w2, b2, out);
}

// Round 12
// 1472.729 us; speedup vs baseline: 1.3747x; 1.3747x over previous
//
#include <hip/hip_runtime.h>
#include <math.h>

#define Bn 128
#define Tn 512
#define Dn 32
#define Hn 128
#define Gn 512   // 4*H
#define Ln 3

// LDS-only barrier: does NOT drain vmcnt.
#define BAR_LDS() asm volatile("s_waitcnt lgkmcnt(0)\n\ts_barrier" ::: "memory")

typedef _Float16 h2 __attribute__((ext_vector_type(2)));

__device__ __forceinline__ float dot2(h2 a, h2 b, float c) {
    return __builtin_amdgcn_fdot2(a, b, c, false);
}
__device__ __forceinline__ h2 pkh(float a, float b) {
    h2 r; r.x = (_Float16)a; r.y = (_Float16)b; return r;
}
__device__ __forceinline__ h2 bcast2(h2 v, int l) {
    int i = __builtin_amdgcn_readlane(__builtin_bit_cast(int, v), l);
    return __builtin_bit_cast(h2, i);
}
__device__ __forceinline__ float sigm(float x) {
    return __builtin_amdgcn_rcpf(1.f + __expf(-x));
}
__device__ __forceinline__ float tanh_fast(float x) {
    return 1.f - 2.f * __builtin_amdgcn_rcpf(1.f + __expf(2.f * x));
}

#define KEEPH(x) asm volatile("" : "+v"(x))
#define DECL16(P, R) \
  h2 P##0=pkh(R[0],R[1]),   P##1=pkh(R[2],R[3]),   P##2=pkh(R[4],R[5]),   P##3=pkh(R[6],R[7]),   \
     P##4=pkh(R[8],R[9]),   P##5=pkh(R[10],R[11]), P##6=pkh(R[12],R[13]), P##7=pkh(R[14],R[15]), \
     P##8=pkh(R[16],R[17]), P##9=pkh(R[18],R[19]), P##10=pkh(R[20],R[21]),P##11=pkh(R[22],R[23]),\
     P##12=pkh(R[24],R[25]),P##13=pkh(R[26],R[27]),P##14=pkh(R[28],R[29]),P##15=pkh(R[30],R[31]);
#define KEEP16(P) \
  KEEPH(P##0); KEEPH(P##1); KEEPH(P##2); KEEPH(P##3); KEEPH(P##4); KEEPH(P##5); \
  KEEPH(P##6); KEEPH(P##7); KEEPH(P##8); KEEPH(P##9); KEEPH(P##10); KEEPH(P##11); \
  KEEPH(P##12); KEEPH(P##13); KEEPH(P##14); KEEPH(P##15);

// 1 broadcast pair feeds 4 dot2 (i,f,g,o share it).
#define DOT4(j) { h2 s = bcast2(hx, j);      \
    aI = dot2(s, wi##j, aI);                 \
    aF = dot2(s, wf##j, aF);                 \
    aG = dot2(s, wg##j, aG);                 \
    aO = dot2(s, wo##j, aO); }

// ---------------------------------------------------------------------------
// fp32 -> fp16 convert (n multiple of 4)
// ---------------------------------------------------------------------------
__global__ __launch_bounds__(256) void cvt_f2h(
    const float* __restrict__ in, _Float16* __restrict__ out, int n)
{
    int base = (blockIdx.x * 256 + threadIdx.x) * 4;
    if (base < n) {
        float4 v = *(const float4*)(in + base);
        *(h2*)(out + base)     = pkh(v.x, v.y);
        *(h2*)(out + base + 2) = pkh(v.z, v.w);
    }
}

// ---------------------------------------------------------------------------
// fp16 GEMM: pre[M, 512] = Ah[M, K] * Wh[512, K]^T + (b_ih + b_hh)
// Tile 128x128, 256 threads, 8x8 outputs/thread, K-chunks of 16 (8 half2),
// inner MAC via v_dot2_f32_f16 (fp32 accumulate).
// ---------------------------------------------------------------------------
__global__ __launch_bounds__(256) void gemm_pre_h(
    const _Float16* __restrict__ A, int K, int rowStrideB, int t0, int tlog,
    const _Float16* __restrict__ W,
    const float* __restrict__ bi, const float* __restrict__ bh,
    float* __restrict__ C)
{
    __shared__ __align__(16) h2 As[8][128];
    __shared__ __align__(16) h2 Bs[8][128];
    const int tid  = threadIdx.x;
    const int row0 = blockIdx.x * 128;
    const int col0 = blockIdx.y * 128;
    const int ty = tid >> 4, tx = tid & 15;
    const int lr = tid >> 1, lk = (tid & 1) * 8;   // k-offset in halfs
    const int ls = lk >> 1;                        // pair-slot offset 0 or 4
    const int tmask = (1 << tlog) - 1;

    float acc[8][8];
    #pragma unroll
    for (int i = 0; i < 8; i++)
        #pragma unroll
        for (int j = 0; j < 8; j++) acc[i][j] = 0.f;

    for (int k0 = 0; k0 < K; k0 += 16) {
        {
            int rg = row0 + lr;
            int b_idx = rg >> tlog;
            int tt = rg & tmask;
            const _Float16* ap = A + (size_t)b_idx * rowStrideB +
                                 (size_t)(t0 + tt) * K + (k0 + lk);
            float4 av = *(const float4*)ap;        // 8 halfs = 4 pairs
            const h2* a2 = (const h2*)&av;
            As[ls + 0][lr] = a2[0]; As[ls + 1][lr] = a2[1];
            As[ls + 2][lr] = a2[2]; As[ls + 3][lr] = a2[3];
            const _Float16* wp = W + (size_t)(col0 + lr) * K + (k0 + lk);
            float4 wv = *(const float4*)wp;
            const h2* w2 = (const h2*)&wv;
            Bs[ls + 0][lr] = w2[0]; Bs[ls + 1][lr] = w2[1];
            Bs[ls + 2][lr] = w2[2]; Bs[ls + 3][lr] = w2[3];
        }
        __syncthreads();
        #pragma unroll
        for (int kk = 0; kk < 8; kk++) {
            h2 a[8], b[8];
            #pragma unroll
            for (int i = 0; i < 8; i++) a[i] = As[kk][ty * 8 + i];
            #pragma unroll
            for (int j = 0; j < 8; j++) b[j] = Bs[kk][tx * 8 + j];
            #pragma unroll
            for (int i = 0; i < 8; i++)
                #pragma unroll
                for (int j = 0; j < 8; j++)
                    acc[i][j] = dot2(a[i], b[j], acc[i][j]);
        }
        __syncthreads();
    }
    #pragma unroll
    for (int i = 0; i < 8; i++) {
        int r = row0 + ty * 8 + i;
        #pragma unroll
        for (int j = 0; j < 8; j += 4) {
            int g = col0 + tx * 8 + j;
            float4 o;
            o.x = acc[i][j + 0] + bi[g + 0] + bh[g + 0];
            o.y = acc[i][j + 1] + bi[g + 1] + bh[g + 1];
            o.z = acc[i][j + 2] + bi[g + 2] + bh[g + 2];
            o.w = acc[i][j + 3] + bi[g + 3] + bh[g + 3];
            *(float4*)&C[(size_t)r * Gn + g] = o;
        }
    }
}

// ---------------------------------------------------------------------------
// LSTM scan v5 (R9 verbatim + fp16 hs16 store). 512 threads, one block per
// batch item. Thread (u = tid&127, kq = tid>>7): gates i,f,g,o of unit u
// over k in [32kq,32kq+32), 64 pinned half2 weights, v_dot2_f32_f16.
// ---------------------------------------------------------------------------
__global__ __launch_bounds__(512)
__attribute__((amdgpu_waves_per_eu(2, 2)))
void lstm_scan(
    const float* __restrict__ pre,     // [B*TCH, 512]
    const float* __restrict__ w_hh,    // [512, 128] (this layer)
    float* __restrict__ hs,            // [B, T, H] layer output (fp32)
    _Float16* __restrict__ hs16,       // [B, T, H] layer output (fp16)
    float* __restrict__ h_state, float* __restrict__ c_state,
    int t0, int TCH, int first)
{
    const int b    = blockIdx.x;
    const int tid  = threadIdx.x;
    const int lane = tid & 63;
    const int u    = tid & 127;        // hidden unit
    const int kq   = tid >> 7;         // k-quarter, wave-uniform

    __shared__ h2 h2_sh[Hn / 2];                 // h as 64 packed pairs
    __shared__ __align__(16) float4 psum[4][Hn]; // slots 1..3 used

    // --- weights: 4 gate rows x 32 k = 16 half2 per gate ---
    const float* rI = w_hh + (size_t)(0 * Hn + u) * Hn + kq * 32;
    const float* rF = w_hh + (size_t)(1 * Hn + u) * Hn + kq * 32;
    const float* rG = w_hh + (size_t)(2 * Hn + u) * Hn + kq * 32;
    const float* rO = w_hh + (size_t)(3 * Hn + u) * Hn + kq * 32;
    DECL16(wi, rI) DECL16(wf, rF) DECL16(wg, rG) DECL16(wo, rO)
    KEEP16(wi) KEEP16(wf) KEEP16(wg) KEEP16(wo)

    float cr = 0.f;
    if (tid < Hn && !first) cr = c_state[b * Hn + tid];
    if (tid < Hn / 2) {
        h2 hv = pkh(0.f, 0.f);
        if (!first) hv = pkh(h_state[b * Hn + 2 * tid],
                             h_state[b * Hn + 2 * tid + 1]);
        h2_sh[tid] = hv;
    }
    __syncthreads();

    // pre pointers: only kq==3 waves touch pre
    const float* ppI = pre + (size_t)b * TCH * Gn + u;
    const float* ppF = ppI + Hn;
    const float* ppG = ppI + 2 * Hn;
    const float* ppO = ppI + 3 * Hn;
    float* hsb = hs + ((size_t)b * Tn + t0) * Hn;
    _Float16* hsb16 = hs16 + ((size_t)b * Tn + t0) * Hn;

    float pI0 = 0.f, pF0 = 0.f, pG0 = 0.f, pO0 = 0.f;
    float pI1 = 0.f, pF1 = 0.f, pG1 = 0.f, pO1 = 0.f;
    if (kq == 3) {
        pI0 = ppI[0]; pF0 = ppF[0]; pG0 = ppG[0]; pO0 = ppO[0];
        if (TCH > 1) { pI1 = ppI[Gn]; pF1 = ppF[Gn]; pG1 = ppG[Gn]; pO1 = ppO[Gn]; }
        else         { pI1 = pI0; pF1 = pF0; pG1 = pG0; pO1 = pO0; }
    }

    const int hslot = kq * 16 + (lane & 15);   // this lane's h-pair cache

    float hlast = 0.f;
    for (int t = 0; t < TCH; t++) {
        h2 hx = h2_sh[hslot];

        float pvI = pI0, pvF = pF0, pvG = pG0, pvO = pO0;
        pI0 = pI1; pF0 = pF1; pG0 = pG1; pO0 = pO1;
        if (kq == 3) {
            int tn = (t + 2 < TCH) ? (t + 2) : (TCH - 1);
            size_t o = (size_t)tn * Gn;
            pI1 = ppI[o]; pF1 = ppF[o]; pG1 = ppG[o]; pO1 = ppO[o];
        }

        float aI = 0.f, aF = 0.f, aG = 0.f, aO = 0.f;
        DOT4(0)  DOT4(1)  DOT4(2)  DOT4(3)
        DOT4(4)  DOT4(5)  DOT4(6)  DOT4(7)
        DOT4(8)  DOT4(9)  DOT4(10) DOT4(11)
        DOT4(12) DOT4(13) DOT4(14) DOT4(15)

        if (kq == 3)
            psum[3][u] = make_float4(aI + pvI, aF + pvF, aG + pvG, aO + pvO);
        else if (kq != 0)
            psum[kq][u] = make_float4(aI, aF, aG, aO);
        BAR_LDS();

        if (tid < Hn) {                 // kq==0: reduce + update
            float4 s1 = psum[1][u], s2 = psum[2][u], s3 = psum[3][u];
            float gi = (aI + s1.x) + (s2.x + s3.x);
            float gf = (aF + s1.y) + (s2.y + s3.y);
            float gg = (aG + s1.z) + (s2.z + s3.z);
            float go = (aO + s1.w) + (s2.w + s3.w);
            float iv = sigm(gi);
            float fv = sigm(gf);
            float gv = tanh_fast(gg);
            float ov = sigm(go);
            cr = fv * cr + iv * gv;
            float hnew = ov * tanh_fast(cr);
            hlast = hnew;
            ((_Float16*)h2_sh)[u] = (_Float16)hnew;   // b16 LDS write
            hsb[(size_t)t * Hn + u] = hnew;           // fp32 trajectory
            hsb16[(size_t)t * Hn + u] = (_Float16)hnew;  // fp16 for next GEMM
        }
        BAR_LDS();
    }

    if (tid < Hn) {
        h_state[b * Hn + u] = hlast;
        c_state[b * Hn + u] = cr;
    }
}

// ---------------------------------------------------------------------------
// Attention pooling + MLP head. One block per batch item, 256 threads.
// ---------------------------------------------------------------------------
__global__ __launch_bounds__(256) void head_kernel(
    const float* __restrict__ hs,
    const float* __restrict__ w_attn, const float* __restrict__ b_attn,
    const float* __restrict__ w1, const float* __restrict__ b1,
    const float* __restrict__ w2, const float* __restrict__ b2,
    float* __restrict__ out)
{
    const int b = blockIdx.x;
    const int tid = threadIdx.x;
    __shared__ __align__(16) float wa_sh[Hn];
    __shared__ __align__(16) float sc[Tn];
    __shared__ __align__(16) float red[256];
    __shared__ __align__(16) float ctx_sh[Hn];
    __shared__ __align__(16) float h1_sh[64];

    if (tid < Hn) wa_sh[tid] = w_attn[tid];
    __syncthreads();

    const float* hb = hs + (size_t)b * Tn * Hn;

    for (int t = tid; t < Tn; t += 256) {
        const float4* hv = (const float4*)(hb + (size_t)t * Hn);
        const float4* wvv = (const float4*)wa_sh;
        float s = 0.f;
        #pragma unroll
        for (int k = 0; k < 32; k++) {
            float4 h4 = hv[k], w4 = wvv[k];
            s += h4.x * w4.x + h4.y * w4.y + h4.z * w4.z + h4.w * w4.w;
        }
        sc[t] = s + b_attn[0];
    }
    __syncthreads();

    float m = fmaxf(sc[tid], sc[tid + 256]);
    red[tid] = m; __syncthreads();
    for (int s_ = 128; s_ > 0; s_ >>= 1) {
        if (tid < s_) red[tid] = fmaxf(red[tid], red[tid + s_]);
        __syncthreads();
    }
    float mx = red[0];
    __syncthreads();
    float e0 = __expf(sc[tid] - mx), e1 = __expf(sc[tid + 256] - mx);
    sc[tid] = e0; sc[tid + 256] = e1;
    red[tid] = e0 + e1; __syncthreads();
    for (int s_ = 128; s_ > 0; s_ >>= 1) {
        if (tid < s_) red[tid] += red[tid + s_];
        __syncthreads();
    }
    float inv = 1.f / red[0];
    __syncthreads();

    {
        int jj = tid & 127, half = tid >> 7;
        float a = 0.f;
        for (int t = half * 256; t < half * 256 + 256; t++)
            a += sc[t] * hb[(size_t)t * Hn + jj];
        red[tid] = a;
        __syncthreads();
        if (tid < Hn) ctx_sh[tid] = (red[tid] + red[tid + Hn]) * inv;
        __syncthreads();
    }

    if (tid < 64) {
        const float4* wvv = (const float4*)(w1 + (size_t)tid * Hn);
        const float4* cv = (const float4*)ctx_sh;
        float s = 0.f;
        #pragma unroll
        for (int k = 0; k < 32; k++) {
            float4 a = wvv[k], c = cv[k];
            s += a.x * c.x + a.y * c.y + a.z * c.z + a.w * c.w;
        }
        h1_sh[tid] = fmaxf(s + b1[tid], 0.f);
    }
    __syncthreads();

    if (tid < 4) {
        float s = 0.f;
        const float* wvv = w2 + tid * 64;
        #pragma unroll
        for (int k = 0; k < 64; k++) s += wvv[k] * h1_sh[k];
        out[b * 4 + tid] = s + b2[tid];
    }
}

// ---------------------------------------------------------------------------
extern "C" void kernel_launch(void* const* d_in, const int* in_sizes, int n_in,
                              void* d_out, int out_size, void* d_ws, size_t ws_size,
                              hipStream_t stream)
{
    const float* x        = (const float*)d_in[0];
    const float* w_ih0    = (const float*)d_in[1];
    const float* w_ih_rest= (const float*)d_in[2];
    const float* w_hh     = (const float*)d_in[3];
    const float* b_ih     = (const float*)d_in[4];
    const float* b_hh     = (const float*)d_in[5];
    const float* w_attn   = (const float*)d_in[6];
    const float* b_attn   = (const float*)d_in[7];
    const float* w1       = (const float*)d_in[8];
    const float* b1       = (const float*)d_in[9];
    const float* w2       = (const float*)d_in[10];
    const float* b2       = (const float*)d_in[11];
    float* out = (float*)d_out;

    const size_t nX  = (size_t)Bn * Tn * Dn;      // 2,097,152
    const size_t nHS = (size_t)Bn * Tn * Hn;      // 8,388,608
    const size_t nW0 = (size_t)Gn * Dn;           // 16,384
    const size_t nWR = (size_t)(Ln - 1) * Gn * Hn;// 131,072

    float* ws   = (float*)d_ws;
    float* hs   = ws;
    float* h_st = hs + nHS;
    float* c_st = h_st + (size_t)Bn * Hn;
    float* pre  = c_st + (size_t)Bn * Hn;

    // pick largest T-chunk that fits in ws (fp32 region + fp16 region)
    const size_t halfBytes = (nX + nHS + nW0 + nWR) * sizeof(_Float16);
    int tch = 512;
    while (tch > 16) {
        size_t need = (nHS + 2 * (size_t)Bn * Hn +
                       (size_t)Bn * tch * Gn) * sizeof(float) + halfBytes;
        if (need <= ws_size) break;
        tch >>= 1;
    }
    int tlog = 31 - __builtin_clz((unsigned)tch);

    _Float16* xh   = (_Float16*)(pre + (size_t)Bn * tch * Gn);
    _Float16* hs16 = xh + nX;
    _Float16* w0h  = hs16 + nHS;
    _Float16* wrh  = w0h + nW0;

    // fp32 -> fp16 conversions (cheap; same work every call)
    cvt_f2h<<<(int)((nX / 4 + 255) / 256), 256, 0, stream>>>(x, xh, (int)nX);
    cvt_f2h<<<(int)((nW0 / 4 + 255) / 256), 256, 0, stream>>>(w_ih0, w0h, (int)nW0);
    cvt_f2h<<<(int)((nWR / 4 + 255) / 256), 256, 0, stream>>>(w_ih_rest, wrh, (int)nWR);

    for (int l = 0; l < Ln; l++) {
        const _Float16* A = (l == 0) ? xh : hs16;
        int K = (l == 0) ? Dn : Hn;
        const _Float16* W = (l == 0) ? w0h : (wrh + (size_t)(l - 1) * Gn * Hn);
        const float* whl = w_hh + (size_t)l * Gn * Hn;
        for (int c = 0; c < Tn / tch; c++) {
            dim3 gg(tch, 4);
            gemm_pre_h<<<gg, 256, 0, stream>>>(A, K, Tn * K, c * tch, tlog,
                                               W, b_ih + l * Gn, b_hh + l * Gn, pre);
            lstm_scan<<<Bn, 512, 0, stream>>>(pre, whl, hs, hs16, h_st, c_st,
                                              c * tch, tch, c == 0 ? 1 : 0);
        }
    }
    head_kernel<<<Bn, 256, 0, stream>>>(hs, w_attn, b_attn, w1, b1, w2, b2, out);
}

// Round 13
// 1262.445 us; speedup vs baseline: 1.6037x; 1.1666x over previous
//
#include <hip/hip_runtime.h>
#include <math.h>

#define Bn 128
#define Tn 512
#define Dn 32
#define Hn 128
#define Gn 512   // 4*H
#define Ln 3

// LDS-only barrier: does NOT drain vmcnt.
#define BAR_LDS() asm volatile("s_waitcnt lgkmcnt(0)\n\ts_barrier" ::: "memory")

typedef _Float16 h2 __attribute__((ext_vector_type(2)));
typedef _Float16 half8 __attribute__((ext_vector_type(8)));   // MFMA A/B frag
typedef float f32x4 __attribute__((ext_vector_type(4)));      // MFMA acc

__device__ __forceinline__ float dot2(h2 a, h2 b, float c) {
    return __builtin_amdgcn_fdot2(a, b, c, false);
}
__device__ __forceinline__ h2 pkh(float a, float b) {
    h2 r; r.x = (_Float16)a; r.y = (_Float16)b; return r;
}
__device__ __forceinline__ h2 bcast2(h2 v, int l) {
    int i = __builtin_amdgcn_readlane(__builtin_bit_cast(int, v), l);
    return __builtin_bit_cast(h2, i);
}
__device__ __forceinline__ float sigm(float x) {
    return __builtin_amdgcn_rcpf(1.f + __expf(-x));
}
__device__ __forceinline__ float tanh_fast(float x) {
    return 1.f - 2.f * __builtin_amdgcn_rcpf(1.f + __expf(2.f * x));
}

#define KEEPH(x) asm volatile("" : "+v"(x))
#define DECL16(P, R) \
  h2 P##0=pkh(R[0],R[1]),   P##1=pkh(R[2],R[3]),   P##2=pkh(R[4],R[5]),   P##3=pkh(R[6],R[7]),   \
     P##4=pkh(R[8],R[9]),   P##5=pkh(R[10],R[11]), P##6=pkh(R[12],R[13]), P##7=pkh(R[14],R[15]), \
     P##8=pkh(R[16],R[17]), P##9=pkh(R[18],R[19]), P##10=pkh(R[20],R[21]),P##11=pkh(R[22],R[23]),\
     P##12=pkh(R[24],R[25]),P##13=pkh(R[26],R[27]),P##14=pkh(R[28],R[29]),P##15=pkh(R[30],R[31]);
#define KEEP16(P) \
  KEEPH(P##0); KEEPH(P##1); KEEPH(P##2); KEEPH(P##3); KEEPH(P##4); KEEPH(P##5); \
  KEEPH(P##6); KEEPH(P##7); KEEPH(P##8); KEEPH(P##9); KEEPH(P##10); KEEPH(P##11); \
  KEEPH(P##12); KEEPH(P##13); KEEPH(P##14); KEEPH(P##15);

#define DOT4(j) { h2 s = bcast2(hx, j);      \
    aI = dot2(s, wi##j, aI);                 \
    aF = dot2(s, wf##j, aF);                 \
    aG = dot2(s, wg##j, aG);                 \
    aO = dot2(s, wo##j, aO); }

// ---------------------------------------------------------------------------
// fp32 -> fp16 convert (n multiple of 4)
// ---------------------------------------------------------------------------
__global__ __launch_bounds__(256) void cvt_f2h(
    const float* __restrict__ in, _Float16* __restrict__ out, int n)
{
    int base = (blockIdx.x * 256 + threadIdx.x) * 4;
    if (base < n) {
        float4 v = *(const float4*)(in + base);
        *(h2*)(out + base)     = pkh(v.x, v.y);
        *(h2*)(out + base + 2) = pkh(v.z, v.w);
    }
}

// ---------------------------------------------------------------------------
// MFMA GEMM: pre[M,512] = Ah[M,K] * Wh[512,K]^T + (b_ih + b_hh)
// 64x64 tile, 256 threads = 4 waves, each wave a 32x32 quadrant as 2x2
// mfma_f32_16x16x32_f16 subtiles. K-chunks of 32. LDS h2[64][20] (80B row
// stride: 16B-aligned, 2-way bank aliasing = free). Fragment layouts per
// verified m89/m120: A[m=lane&15][k=(lane>>4)*8+j], C/D row=(lane>>4)*4+reg,
// col=lane&15.
// ---------------------------------------------------------------------------
__global__ __launch_bounds__(256) void gemm_pre_mfma(
    const _Float16* __restrict__ A, int K, int rowStrideB, int t0, int tlog,
    const _Float16* __restrict__ W,
    const float* __restrict__ bi, const float* __restrict__ bh,
    float* __restrict__ C)
{
    __shared__ h2 As2[64][20];
    __shared__ h2 Bs2[64][20];
    const int tid  = threadIdx.x;
    const int row0 = blockIdx.x * 64;
    const int col0 = blockIdx.y * 64;
    const int w    = tid >> 6;
    const int lane = tid & 63;
    const int qm   = (w >> 1) * 32;
    const int qn   = (w & 1) * 32;
    const int fm   = lane & 15;
    const int fq   = lane >> 4;
    const int tmask = (1 << tlog) - 1;
    const int lrow = tid >> 2;          // staging row 0..63
    const int lk   = (tid & 3) * 8;     // staging k-offset (halfs)

    f32x4 acc00 = {0,0,0,0}, acc01 = {0,0,0,0};
    f32x4 acc10 = {0,0,0,0}, acc11 = {0,0,0,0};

    for (int k0 = 0; k0 < K; k0 += 32) {
        {
            int rg = row0 + lrow;
            int b_idx = rg >> tlog, tt = rg & tmask;
            const _Float16* ap = A + (size_t)b_idx * rowStrideB +
                                 (size_t)(t0 + tt) * K + (k0 + lk);
            *(float4*)&As2[lrow][(tid & 3) * 4] = *(const float4*)ap;
            const _Float16* wp = W + (size_t)(col0 + lrow) * K + (k0 + lk);
            *(float4*)&Bs2[lrow][(tid & 3) * 4] = *(const float4*)wp;
        }
        __syncthreads();
        half8 a0 = *(const half8*)&As2[qm + fm][fq * 4];
        half8 a1 = *(const half8*)&As2[qm + 16 + fm][fq * 4];
        half8 b0 = *(const half8*)&Bs2[qn + fm][fq * 4];
        half8 b1 = *(const half8*)&Bs2[qn + 16 + fm][fq * 4];
        acc00 = __builtin_amdgcn_mfma_f32_16x16x32_f16(a0, b0, acc00, 0, 0, 0);
        acc01 = __builtin_amdgcn_mfma_f32_16x16x32_f16(a0, b1, acc01, 0, 0, 0);
        acc10 = __builtin_amdgcn_mfma_f32_16x16x32_f16(a1, b0, acc10, 0, 0, 0);
        acc11 = __builtin_amdgcn_mfma_f32_16x16x32_f16(a1, b1, acc11, 0, 0, 0);
        __syncthreads();
    }

    const int g0 = col0 + qn + fm;
    const int g1 = g0 + 16;
    const float bb0 = bi[g0] + bh[g0];
    const float bb1 = bi[g1] + bh[g1];
    const int m0 = row0 + qm + fq * 4;
    #pragma unroll
    for (int r = 0; r < 4; r++) {
        C[(size_t)(m0 + r) * Gn + g0]      = acc00[r] + bb0;
        C[(size_t)(m0 + r) * Gn + g1]      = acc01[r] + bb1;
        C[(size_t)(m0 + 16 + r) * Gn + g0] = acc10[r] + bb0;
        C[(size_t)(m0 + 16 + r) * Gn + g1] = acc11[r] + bb1;
    }
}

// ---------------------------------------------------------------------------
// LSTM scan v5 (R9 structure), fp16-only trajectory store.
// 512 threads, one block per batch item. Thread (u = tid&127, kq = tid>>7):
// gates i,f,g,o of unit u over k in [32kq,32kq+32), 64 pinned half2 weights,
// v_dot2_f32_f16 (fp32 accumulate).
// ---------------------------------------------------------------------------
__global__ __launch_bounds__(512)
__attribute__((amdgpu_waves_per_eu(2, 2)))
void lstm_scan(
    const float* __restrict__ pre,     // [B*TCH, 512]
    const float* __restrict__ w_hh,    // [512, 128] (this layer)
    _Float16* __restrict__ hs16,       // [B, T, H] layer output (fp16)
    float* __restrict__ h_state, float* __restrict__ c_state,
    int t0, int TCH, int first)
{
    const int b    = blockIdx.x;
    const int tid  = threadIdx.x;
    const int lane = tid & 63;
    const int u    = tid & 127;        // hidden unit
    const int kq   = tid >> 7;         // k-quarter, wave-uniform

    __shared__ h2 h2_sh[Hn / 2];                 // h as 64 packed pairs
    __shared__ __align__(16) float4 psum[4][Hn]; // slots 1..3 used

    const float* rI = w_hh + (size_t)(0 * Hn + u) * Hn + kq * 32;
    const float* rF = w_hh + (size_t)(1 * Hn + u) * Hn + kq * 32;
    const float* rG = w_hh + (size_t)(2 * Hn + u) * Hn + kq * 32;
    const float* rO = w_hh + (size_t)(3 * Hn + u) * Hn + kq * 32;
    DECL16(wi, rI) DECL16(wf, rF) DECL16(wg, rG) DECL16(wo, rO)
    KEEP16(wi) KEEP16(wf) KEEP16(wg) KEEP16(wo)

    float cr = 0.f;
    if (tid < Hn && !first) cr = c_state[b * Hn + tid];
    if (tid < Hn / 2) {
        h2 hv = pkh(0.f, 0.f);
        if (!first) hv = pkh(h_state[b * Hn + 2 * tid],
                             h_state[b * Hn + 2 * tid + 1]);
        h2_sh[tid] = hv;
    }
    __syncthreads();

    const float* ppI = pre + (size_t)b * TCH * Gn + u;
    const float* ppF = ppI + Hn;
    const float* ppG = ppI + 2 * Hn;
    const float* ppO = ppI + 3 * Hn;
    _Float16* hsb16 = hs16 + ((size_t)b * Tn + t0) * Hn;

    float pI0 = 0.f, pF0 = 0.f, pG0 = 0.f, pO0 = 0.f;
    float pI1 = 0.f, pF1 = 0.f, pG1 = 0.f, pO1 = 0.f;
    if (kq == 3) {
        pI0 = ppI[0]; pF0 = ppF[0]; pG0 = ppG[0]; pO0 = ppO[0];
        if (TCH > 1) { pI1 = ppI[Gn]; pF1 = ppF[Gn]; pG1 = ppG[Gn]; pO1 = ppO[Gn]; }
        else         { pI1 = pI0; pF1 = pF0; pG1 = pG0; pO1 = pO0; }
    }

    const int hslot = kq * 16 + (lane & 15);

    float hlast = 0.f;
    for (int t = 0; t < TCH; t++) {
        h2 hx = h2_sh[hslot];

        float pvI = pI0, pvF = pF0, pvG = pG0, pvO = pO0;
        pI0 = pI1; pF0 = pF1; pG0 = pG1; pO0 = pO1;
        if (kq == 3) {
            int tn = (t + 2 < TCH) ? (t + 2) : (TCH - 1);
            size_t o = (size_t)tn * Gn;
            pI1 = ppI[o]; pF1 = ppF[o]; pG1 = ppG[o]; pO1 = ppO[o];
        }

        float aI = 0.f, aF = 0.f, aG = 0.f, aO = 0.f;
        DOT4(0)  DOT4(1)  DOT4(2)  DOT4(3)
        DOT4(4)  DOT4(5)  DOT4(6)  DOT4(7)
        DOT4(8)  DOT4(9)  DOT4(10) DOT4(11)
        DOT4(12) DOT4(13) DOT4(14) DOT4(15)

        if (kq == 3)
            psum[3][u] = make_float4(aI + pvI, aF + pvF, aG + pvG, aO + pvO);
        else if (kq != 0)
            psum[kq][u] = make_float4(aI, aF, aG, aO);
        BAR_LDS();

        if (tid < Hn) {                 // kq==0: reduce + update
            float4 s1 = psum[1][u], s2 = psum[2][u], s3 = psum[3][u];
            float gi = (aI + s1.x) + (s2.x + s3.x);
            float gf = (aF + s1.y) + (s2.y + s3.y);
            float gg = (aG + s1.z) + (s2.z + s3.z);
            float go = (aO + s1.w) + (s2.w + s3.w);
            float iv = sigm(gi);
            float fv = sigm(gf);
            float gv = tanh_fast(gg);
            float ov = sigm(go);
            cr = fv * cr + iv * gv;
            float hnew = ov * tanh_fast(cr);
            hlast = hnew;
            _Float16 hh = (_Float16)hnew;
            ((_Float16*)h2_sh)[u] = hh;               // b16 LDS write
            hsb16[(size_t)t * Hn + u] = hh;           // fp16 trajectory only
        }
        BAR_LDS();
    }

    if (tid < Hn) {
        h_state[b * Hn + u] = hlast;
        c_state[b * Hn + u] = cr;
    }
}

// ---------------------------------------------------------------------------
// Attention pooling + MLP head (reads fp16 hs). One block per batch item.
// ---------------------------------------------------------------------------
__global__ __launch_bounds__(256) void head_kernel(
    const _Float16* __restrict__ hs16,
    const float* __restrict__ w_attn, const float* __restrict__ b_attn,
    const float* __restrict__ w1, const float* __restrict__ b1,
    const float* __restrict__ w2, const float* __restrict__ b2,
    float* __restrict__ out)
{
    const int b = blockIdx.x;
    const int tid = threadIdx.x;
    __shared__ h2 wa2[Hn / 2];
    __shared__ __align__(16) float sc[Tn];
    __shared__ __align__(16) float red[256];
    __shared__ __align__(16) float ctx_sh[Hn];
    __shared__ __align__(16) float h1_sh[64];

    if (tid < Hn / 2) wa2[tid] = pkh(w_attn[2 * tid], w_attn[2 * tid + 1]);
    __syncthreads();

    const _Float16* hb = hs16 + (size_t)b * Tn * Hn;

    for (int t = tid; t < Tn; t += 256) {
        const h2* hp = (const h2*)(hb + (size_t)t * Hn);
        float s = 0.f;
        #pragma unroll
        for (int k = 0; k < 64; k++) s = dot2(hp[k], wa2[k], s);
        sc[t] = s + b_attn[0];
    }
    __syncthreads();

    float m = fmaxf(sc[tid], sc[tid + 256]);
    red[tid] = m; __syncthreads();
    for (int s_ = 128; s_ > 0; s_ >>= 1) {
        if (tid < s_) red[tid] = fmaxf(red[tid], red[tid + s_]);
        __syncthreads();
    }
    float mx = red[0];
    __syncthreads();
    float e0 = __expf(sc[tid] - mx), e1 = __expf(sc[tid + 256] - mx);
    sc[tid] = e0; sc[tid + 256] = e1;
    red[tid] = e0 + e1; __syncthreads();
    for (int s_ = 128; s_ > 0; s_ >>= 1) {
        if (tid < s_) red[tid] += red[tid + s_];
        __syncthreads();
    }
    float inv = 1.f / red[0];
    __syncthreads();

    {
        int jj = tid & 127, half = tid >> 7;
        float a = 0.f;
        for (int t = half * 256; t < half * 256 + 256; t++)
            a += sc[t] * (float)hb[(size_t)t * Hn + jj];
        red[tid] = a;
        __syncthreads();
        if (tid < Hn) ctx_sh[tid] = (red[tid] + red[tid + Hn]) * inv;
        __syncthreads();
    }

    if (tid < 64) {
        const float4* wvv = (const float4*)(w1 + (size_t)tid * Hn);
        const float4* cv = (const float4*)ctx_sh;
        float s = 0.f;
        #pragma unroll
        for (int k = 0; k < 32; k++) {
            float4 a = wvv[k], c = cv[k];
            s += a.x * c.x + a.y * c.y + a.z * c.z + a.w * c.w;
        }
        h1_sh[tid] = fmaxf(s + b1[tid], 0.f);
    }
    __syncthreads();

    if (tid < 4) {
        float s = 0.f;
        const float* wvv = w2 + tid * 64;
        #pragma unroll
        for (int k = 0; k < 64; k++) s += wvv[k] * h1_sh[k];
        out[b * 4 + tid] = s + b2[tid];
    }
}

// ---------------------------------------------------------------------------
extern "C" void kernel_launch(void* const* d_in, const int* in_sizes, int n_in,
                              void* d_out, int out_size, void* d_ws, size_t ws_size,
                              hipStream_t stream)
{
    const float* x        = (const float*)d_in[0];
    const float* w_ih0    = (const float*)d_in[1];
    const float* w_ih_rest= (const float*)d_in[2];
    const float* w_hh     = (const float*)d_in[3];
    const float* b_ih     = (const float*)d_in[4];
    const float* b_hh     = (const float*)d_in[5];
    const float* w_attn   = (const float*)d_in[6];
    const float* b_attn   = (const float*)d_in[7];
    const float* w1       = (const float*)d_in[8];
    const float* b1       = (const float*)d_in[9];
    const float* w2       = (const float*)d_in[10];
    const float* b2       = (const float*)d_in[11];
    float* out = (float*)d_out;

    const size_t nX  = (size_t)Bn * Tn * Dn;       // 2,097,152
    const size_t nHS = (size_t)Bn * Tn * Hn;       // 8,388,608
    const size_t nW0 = (size_t)Gn * Dn;            // 16,384
    const size_t nWR = (size_t)(Ln - 1) * Gn * Hn; // 131,072

    float* ws   = (float*)d_ws;
    float* h_st = ws;
    float* c_st = h_st + (size_t)Bn * Hn;
    float* pre  = c_st + (size_t)Bn * Hn;

    const size_t halfBytes = (nX + nHS + nW0 + nWR) * sizeof(_Float16);
    int tch = 512;
    while (tch > 64) {
        size_t need = (2 * (size_t)Bn * Hn +
                       (size_t)Bn * tch * Gn) * sizeof(float) + halfBytes;
        if (need <= ws_size) break;
        tch >>= 1;
    }
    int tlog = 31 - __builtin_clz((unsigned)tch);

    _Float16* xh   = (_Float16*)(pre + (size_t)Bn * tch * Gn);
    _Float16* hs16 = xh + nX;
    _Float16* w0h  = hs16 + nHS;
    _Float16* wrh  = w0h + nW0;

    cvt_f2h<<<(int)((nX / 4 + 255) / 256), 256, 0, stream>>>(x, xh, (int)nX);
    cvt_f2h<<<(int)((nW0 / 4 + 255) / 256), 256, 0, stream>>>(w_ih0, w0h, (int)nW0);
    cvt_f2h<<<(int)((nWR / 4 + 255) / 256), 256, 0, stream>>>(w_ih_rest, wrh, (int)nWR);

    for (int l = 0; l < Ln; l++) {
        const _Float16* A = (l == 0) ? xh : hs16;
        int K = (l == 0) ? Dn : Hn;
        const _Float16* W = (l == 0) ? w0h : (wrh + (size_t)(l - 1) * Gn * Hn);
        const float* whl = w_hh + (size_t)l * Gn * Hn;
        for (int c = 0; c < Tn / tch; c++) {
            dim3 gg(Bn * tch / 64, 8);
            gemm_pre_mfma<<<gg, 256, 0, stream>>>(A, K, Tn * K, c * tch, tlog,
                                                  W, b_ih + l * Gn, b_hh + l * Gn, pre);
            lstm_scan<<<Bn, 512, 0, stream>>>(pre, whl, hs16, h_st, c_st,
                                              c * tch, tch, c == 0 ? 1 : 0);
        }
    }
    head_kernel<<<Bn, 256, 0, stream>>>(hs16, w_attn, b_attn, w1, b1, w2, b2, out);
}